// Round 5
// baseline (1251.770 us; speedup 1.0000x reference)
//
#include <hip/hip_runtime.h>

// MsgPassingNN: 3 rounds of edge-MLP + segment_sum + node-MLP.
// N=100000 nodes (D=16), E=3200000 edges.
// fe: 32 -> 9 (relu) -> 9 (relu) -> 9 ; fx: 25 -> 9 (relu) -> 9 (relu) -> 16
//
// R7 structure (vs R6):
//   * lsort_k DELETED: LDS-tile reduction needs only bucket-level grouping,
//     not in-bucket dst order. Sort = single bsort_k pass (bucket = dst>>7).
//   * edge6_k replaces scan+global-atomics with a 128x9 LDS tile + ds_add_f32:
//     256 threads, 4 edges/thread over 1024 consecutive slots; staged
//     uint4 sed load -> 4 gathers in flight -> 4 MLPs -> 9 LDS atomics each.
//     base1 tile (128x12) staged in LDS. Flush = plain coalesced stores into
//     8 SoA partial arrays mq[(q*9+j)*NN + n]; empty blocks store zeros.
//     ZERO global atomics in all rounds.
//   * node5_k sums the 8 partials (72 coalesced loads), fx MLP, writes out
//     in place, recomputes base1/base_s for next round. No m zeroing needed.
//   * fe layer-1 stays fully hoisted per node (base1 = W1d^T x + b1 stride 12,
//     base_s = W1s^T x stride 16/64B rows); edge = 9 adds + relu + 2x 9x9.

constexpr int NN = 100000;
constexpr int NE = 3200000;
constexpr int NBK = (NN + 127) / 128;      // 782 buckets of 128 nodes
constexpr int SLOT = 8192;                 // sed slots per bucket (avg fill 4096)
constexpr int EPB = 4096;                  // edges per bsort block (16/thread)
constexpr int NBLK_SORT = (NE + EPB - 1) / EPB;   // 782
constexpr int NB_NODE = (NN + 255) / 256;  // 391
constexpr int EPBLK = 1024;                // slots per edge block
constexpr int QPB = SLOT / EPBLK;          // 8 partials per bucket

// ---------------- bucket cursor init ----------------

__global__ __launch_bounds__(256) void init_k(int* __restrict__ gcursor)
{
    int i = blockIdx.x * 256 + threadIdx.x;
    if (i < NBK) gcursor[i] = i * SLOT;
}

// ---------------- one-pass bucket sort (dst>>7) ----------------

__global__ __launch_bounds__(256) void bsort_k(const int* __restrict__ src,
                                               const int* __restrict__ dst,
                                               int* __restrict__ gcursor,
                                               unsigned* __restrict__ sed)
{
    __shared__ int lhist[NBK];
    __shared__ int lbase[NBK];
    const int t = threadIdx.x;
    for (int i = t; i < NBK; i += 256) lhist[i] = 0;
    __syncthreads();

    const int blkbase = blockIdx.x * EPB;
    unsigned pr[16], sv[16];
    #pragma unroll
    for (int k = 0; k < 16; ++k) {
        const int e = blkbase + k * 256 + t;
        if (e < NE) {
            const int d = dst[e];
            const int s = src[e];
            const int bin = d >> 7;
            const int r = atomicAdd(&lhist[bin], 1);      // LDS atomic
            pr[k] = ((unsigned)bin << 13) | (unsigned)r;  // r < 4096 < 2^13
            sv[k] = ((unsigned)(d & 127) << 17) | (unsigned)s;
        } else {
            pr[k] = 0xFFFFFFFFu;
        }
    }
    __syncthreads();

    for (int i = t; i < NBK; i += 256) {
        const int c = lhist[i];
        if (c) lbase[i] = atomicAdd(&gcursor[i], c);      // 1 global atomic/(block,bin)
    }
    __syncthreads();

    #pragma unroll
    for (int k = 0; k < 16; ++k) {
        if (pr[k] != 0xFFFFFFFFu) {
            const int bin = (int)(pr[k] >> 13);
            const int r = (int)(pr[k] & 0x1FFFu);
            sed[lbase[bin] + r] = sv[k];
        }
    }
}

// ---------------- round-0 prologue: base1 + base_s from X0 ----------------

__global__ __launch_bounds__(256) void base_k(const float* __restrict__ X,
                                              const float* __restrict__ feW1,
                                              const float* __restrict__ feb1,
                                              float* __restrict__ base1,
                                              float* __restrict__ bases)
{
    __shared__ float sW[32 * 12], sb[9];
    const int t = threadIdx.x;
    for (int i = t; i < 288; i += 256) sW[(i / 9) * 12 + (i % 9)] = feW1[i];
    if (t < 9) sb[t] = feb1[t];
    __syncthreads();

    const int n = blockIdx.x * 256 + t;
    if (n >= NN) return;

    float x[16];
    const float4* p = reinterpret_cast<const float4*>(X + (size_t)n * 16);
    #pragma unroll
    for (int q = 0; q < 4; ++q) {
        float4 v = p[q];
        x[4*q] = v.x; x[4*q+1] = v.y; x[4*q+2] = v.z; x[4*q+3] = v.w;
    }
    float bd[9];
    #pragma unroll
    for (int j = 0; j < 9; ++j) bd[j] = sb[j];
    #pragma unroll
    for (int i = 0; i < 16; ++i) {
        const float xi = x[i];
        #pragma unroll
        for (int j = 0; j < 9; ++j) bd[j] = fmaf(xi, sW[i * 12 + j], bd[j]);
    }
    float bs[9];
    #pragma unroll
    for (int j = 0; j < 9; ++j) bs[j] = 0.f;
    #pragma unroll
    for (int i = 0; i < 16; ++i) {
        const float xi = x[i];
        #pragma unroll
        for (int j = 0; j < 9; ++j) bs[j] = fmaf(xi, sW[(16 + i) * 12 + j], bs[j]);
    }
    float* bp = base1 + (size_t)n * 12;
    #pragma unroll
    for (int j = 0; j < 9; ++j) bp[j] = bd[j];
    float* sp = bases + (size_t)n * 16;
    #pragma unroll
    for (int j = 0; j < 9; ++j) sp[j] = bs[j];
}

// ---------------- edge round: LDS-tile reduction, 4 edges/thread ----------------

__global__ __launch_bounds__(256, 6) void edge6_k(
    const float* __restrict__ base1,
    const float* __restrict__ bases,
    const unsigned* __restrict__ sed,
    const int* __restrict__ gcursor,
    const float* __restrict__ feW2, const float* __restrict__ feb2,
    const float* __restrict__ feW3, const float* __restrict__ feb3,
    float* __restrict__ mq)   // SoA: mq[(q*9+j)*NN + n]
{
    const int t = threadIdx.x;
    const int b = blockIdx.x >> 3;          // bucket
    const int q = blockIdx.x & (QPB - 1);   // partial index
    const int nbase = b * 128;
    const int fill = gcursor[b] - b * SLOT;
    const int lo = q * EPBLK;

    if (lo >= fill) {
        // this partial sees no edges: store zeros (coalesced), done
        #pragma unroll
        for (int i = t; i < 128 * 9; i += 256) {
            const int dl = i & 127, j = i >> 7;
            if (nbase + dl < NN) mq[(size_t)(q * 9 + j) * NN + nbase + dl] = 0.f;
        }
        return;
    }

    __shared__ float sW2[9 * 12], sW3[9 * 12], sb2[9], sb3[9];
    __shared__ float b1l[128 * 12];   // base1 tile, float4-readable rows
    __shared__ float ml[128 * 9];     // message accumulator tile
    if (t < 81)  sW2[(t / 9) * 12 + (t % 9)] = feW2[t];
    if (t >= 128 && t < 209) { int i = t - 128; sW3[(i / 9) * 12 + (i % 9)] = feW3[i]; }
    if (t >= 224 && t < 233) sb2[t - 224] = feb2[t - 224];
    if (t >= 240 && t < 249) sb3[t - 240] = feb3[t - 240];
    {
        const int nn12 = ((NN - nbase < 128) ? (NN - nbase) : 128) * 12;
        for (int i = t; i < nn12; i += 256) b1l[i] = base1[(size_t)nbase * 12 + i];
        for (int i = t; i < 128 * 9; i += 256) ml[i] = 0.f;
    }
    __syncthreads();

    const int cap = (fill < lo + EPBLK) ? fill : lo + EPBLK;
    const int myslot = lo + t * 4;

    unsigned pk0 = 0, pk1 = 0, pk2 = 0, pk3 = 0;
    if (myslot < cap) {
        const uint4 p4 = *reinterpret_cast<const uint4*>(sed + (size_t)b * SLOT + myslot);
        pk0 = p4.x; pk1 = p4.y; pk2 = p4.z; pk3 = p4.w;
    }
    const unsigned pks[4] = {pk0, pk1, pk2, pk3};

    // stage 1: issue all gathers (4 independent chains in flight)
    float A[4][9];
    int DL[4];
    bool V[4];
    #pragma unroll
    for (int k = 0; k < 4; ++k) {
        V[k] = (myslot + k) < cap;
        const unsigned pk = pks[k];
        const int dl = V[k] ? (int)(pk >> 17) : 0;
        const int s  = (int)(pk & 0x1FFFFu);
        DL[k] = dl;
        float4 c0, c1; float c8;
        if (V[k]) {
            const float4* ps = reinterpret_cast<const float4*>(bases + (size_t)s * 16);
            c0 = ps[0]; c1 = ps[1]; c8 = bases[(size_t)s * 16 + 8];
        } else {
            c0 = float4{0.f, 0.f, 0.f, 0.f}; c1 = c0; c8 = 0.f;
        }
        const float4* pb = reinterpret_cast<const float4*>(&b1l[dl * 12]);
        const float4 b0 = pb[0], b1v = pb[1];
        const float b8 = b1l[dl * 12 + 8];
        A[k][0] = b0.x + c0.x; A[k][1] = b0.y + c0.y; A[k][2] = b0.z + c0.z; A[k][3] = b0.w + c0.w;
        A[k][4] = b1v.x + c1.x; A[k][5] = b1v.y + c1.y; A[k][6] = b1v.z + c1.z; A[k][7] = b1v.w + c1.w;
        A[k][8] = b8 + c8;
    }

    // stage 2: MLP per edge, accumulate into LDS tile
    #pragma unroll
    for (int k = 0; k < 4; ++k) {
        float a[9];
        #pragma unroll
        for (int j = 0; j < 9; ++j) a[j] = fmaxf(A[k][j], 0.f);

        float h2[9];
        #pragma unroll
        for (int j = 0; j < 9; ++j) h2[j] = sb2[j];
        #pragma unroll
        for (int i = 0; i < 9; ++i) {
            const float ai = a[i];
            #pragma unroll
            for (int j = 0; j < 9; ++j) h2[j] = fmaf(ai, sW2[i * 12 + j], h2[j]);
        }
        #pragma unroll
        for (int j = 0; j < 9; ++j) h2[j] = fmaxf(h2[j], 0.f);

        float o[9];
        #pragma unroll
        for (int j = 0; j < 9; ++j) o[j] = sb3[j];
        #pragma unroll
        for (int i = 0; i < 9; ++i) {
            const float hi = h2[i];
            #pragma unroll
            for (int j = 0; j < 9; ++j) o[j] = fmaf(hi, sW3[i * 12 + j], o[j]);
        }

        if (V[k]) {
            const int d9 = DL[k] * 9;
            #pragma unroll
            for (int j = 0; j < 9; ++j) atomicAdd(&ml[d9 + j], o[j]);  // ds_add_f32
        }
    }
    __syncthreads();

    // flush: plain coalesced stores into this block's SoA partial
    #pragma unroll
    for (int i = t; i < 128 * 9; i += 256) {
        const int dl = i & 127, j = i >> 7;
        if (nbase + dl < NN) mq[(size_t)(q * 9 + j) * NN + nbase + dl] = ml[dl * 9 + j];
    }
}

// ---------------- node round: sum partials + fx MLP + next base1/base_s ----------------

__global__ __launch_bounds__(256) void node5_k(
    const float* __restrict__ Xin, const float* __restrict__ mq,
    const float* __restrict__ fxW1, const float* __restrict__ fxb1,
    const float* __restrict__ fxW2, const float* __restrict__ fxb2,
    const float* __restrict__ fxW3, const float* __restrict__ fxb3,
    const float* __restrict__ feW1, const float* __restrict__ feb1,
    float* __restrict__ Xout, float* __restrict__ base1out,
    float* __restrict__ basesout)
{
    __shared__ float sU1[25 * 12], sU2[9 * 12], sU3[9 * 16];
    __shared__ float sW1d[16 * 12], sW1s[16 * 12];
    __shared__ float sNB[34], sEB1[9];
    const int t = threadIdx.x;
    if (t < 225) sU1[(t / 9) * 12 + (t % 9)] = fxW1[t];
    if (t < 81)  sU2[(t / 9) * 12 + (t % 9)] = fxW2[t];
    if (t < 144) sU3[t] = fxW3[t];
    if (t < 144) sW1d[(t / 9) * 12 + (t % 9)] = feW1[t];
    if (t >= 112) { int i = t - 112; sW1s[(i / 9) * 12 + (i % 9)] = feW1[144 + i]; }
    if (t < 9) sNB[t] = fxb1[t];
    if (t >= 32 && t < 41) sNB[9 + (t - 32)] = fxb2[t - 32];
    if (t >= 64 && t < 80) sNB[18 + (t - 64)] = fxb3[t - 64];
    if (t >= 96 && t < 105) sEB1[t - 96] = feb1[t - 96];
    __syncthreads();

    const int n = blockIdx.x * 256 + t;
    if (n >= NN) return;

    float xr[16];
    {
        const float4* p = reinterpret_cast<const float4*>(Xin + (size_t)n * 16);
        #pragma unroll
        for (int q = 0; q < 4; ++q) {
            float4 v = p[q];
            xr[4*q] = v.x; xr[4*q+1] = v.y; xr[4*q+2] = v.z; xr[4*q+3] = v.w;
        }
    }
    // sum the QPB SoA partials (72 coalesced loads)
    float mm[9];
    #pragma unroll
    for (int j = 0; j < 9; ++j) mm[j] = 0.f;
    #pragma unroll
    for (int qq = 0; qq < QPB; ++qq) {
        #pragma unroll
        for (int j = 0; j < 9; ++j) mm[j] += mq[(size_t)(qq * 9 + j) * NN + n];
    }

    float h1[9];
    #pragma unroll
    for (int j = 0; j < 9; ++j) h1[j] = sNB[j];
    #pragma unroll
    for (int i = 0; i < 16; ++i) {
        const float xi = xr[i];
        #pragma unroll
        for (int j = 0; j < 9; ++j) h1[j] = fmaf(xi, sU1[i * 12 + j], h1[j]);
    }
    #pragma unroll
    for (int i = 0; i < 9; ++i) {
        const float xi = mm[i];
        #pragma unroll
        for (int j = 0; j < 9; ++j) h1[j] = fmaf(xi, sU1[(16 + i) * 12 + j], h1[j]);
    }
    #pragma unroll
    for (int j = 0; j < 9; ++j) h1[j] = fmaxf(h1[j], 0.f);

    float h2[9];
    #pragma unroll
    for (int j = 0; j < 9; ++j) h2[j] = sNB[9 + j];
    #pragma unroll
    for (int i = 0; i < 9; ++i) {
        const float xi = h1[i];
        #pragma unroll
        for (int j = 0; j < 9; ++j) h2[j] = fmaf(xi, sU2[i * 12 + j], h2[j]);
    }
    #pragma unroll
    for (int j = 0; j < 9; ++j) h2[j] = fmaxf(h2[j], 0.f);

    float o[16];
    #pragma unroll
    for (int k = 0; k < 16; ++k) o[k] = sNB[18 + k];
    #pragma unroll
    for (int j = 0; j < 9; ++j) {
        const float hj = h2[j];
        #pragma unroll
        for (int k = 0; k < 16; ++k) o[k] = fmaf(hj, sU3[j * 16 + k], o[k]);
    }

    float4* po = reinterpret_cast<float4*>(Xout + (size_t)n * 16);
    #pragma unroll
    for (int q = 0; q < 4; ++q) {
        float4 v;
        v.x = o[4*q]; v.y = o[4*q+1]; v.z = o[4*q+2]; v.w = o[4*q+3];
        po[q] = v;
    }

    // base1 / base_s for NEXT round's edge kernel
    float bb[9];
    #pragma unroll
    for (int j = 0; j < 9; ++j) bb[j] = sEB1[j];
    #pragma unroll
    for (int i = 0; i < 16; ++i) {
        const float xi = o[i];
        #pragma unroll
        for (int j = 0; j < 9; ++j) bb[j] = fmaf(xi, sW1d[i * 12 + j], bb[j]);
    }
    float* bp = base1out + (size_t)n * 12;
    #pragma unroll
    for (int j = 0; j < 9; ++j) bp[j] = bb[j];

    float cc[9];
    #pragma unroll
    for (int j = 0; j < 9; ++j) cc[j] = 0.f;
    #pragma unroll
    for (int i = 0; i < 16; ++i) {
        const float xi = o[i];
        #pragma unroll
        for (int j = 0; j < 9; ++j) cc[j] = fmaf(xi, sW1s[i * 12 + j], cc[j]);
    }
    float* sp = basesout + (size_t)n * 16;
    #pragma unroll
    for (int j = 0; j < 9; ++j) sp[j] = cc[j];
}

extern "C" void kernel_launch(void* const* d_in, const int* in_sizes, int n_in,
                              void* d_out, int out_size, void* d_ws, size_t ws_size,
                              hipStream_t stream)
{
    (void)in_sizes; (void)n_in; (void)out_size; (void)ws_size;
    const float* X0   = (const float*)d_in[0];
    const int*   esrc = (const int*)d_in[1];
    const int*   edst = (const int*)d_in[2];
    const float* feW1 = (const float*)d_in[3];
    const float* feb1 = (const float*)d_in[4];
    const float* feW2 = (const float*)d_in[5];
    const float* feb2 = (const float*)d_in[6];
    const float* feW3 = (const float*)d_in[7];
    const float* feb3 = (const float*)d_in[8];
    const float* fxW1 = (const float*)d_in[9];
    const float* fxb1 = (const float*)d_in[10];
    const float* fxW2 = (const float*)d_in[11];
    const float* fxb2 = (const float*)d_in[12];
    const float* fxW3 = (const float*)d_in[13];
    const float* fxb3 = (const float*)d_in[14];
    float* out = (float*)d_out;

    // workspace layout (floats unless noted). total ~66 MB.
    float* base1  = (float*)d_ws;                         // NN*12
    float* bases  = base1 + (size_t)NN * 12;              // NN*16 (64B rows)
    float* mq     = bases + (size_t)NN * 16;              // QPB*9*NN SoA partials
    int* gcursor  = (int*)(mq + (size_t)QPB * 9 * NN);    // NBK (padded to 1024)
    unsigned* sed = (unsigned*)(gcursor + 1024);          // NBK*SLOT u32 = 25.6MB

    const dim3 thr(256);
    const dim3 gS(NBLK_SORT);          // 782
    const dim3 gE(NBK * QPB);          // 6256
    const dim3 gN(NB_NODE);            // 391

    // ---- bucket sort (once per launch) ----
    init_k<<<4, thr, 0, stream>>>(gcursor);
    bsort_k<<<gS, thr, 0, stream>>>(esrc, edst, gcursor, sed);

    // ---- round 0 ----
    base_k<<<gN, thr, 0, stream>>>(X0, feW1, feb1, base1, bases);
    edge6_k<<<gE, thr, 0, stream>>>(base1, bases, sed, gcursor,
                                    feW2, feb2, feW3, feb3, mq);
    node5_k<<<gN, thr, 0, stream>>>(X0, mq, fxW1, fxb1, fxW2, fxb2, fxW3, fxb3,
                                    feW1, feb1, out, base1, bases);
    // ---- round 1 (node updates out in place; edge never reads X) ----
    edge6_k<<<gE, thr, 0, stream>>>(base1, bases, sed, gcursor,
                                    feW2, feb2, feW3, feb3, mq);
    node5_k<<<gN, thr, 0, stream>>>(out, mq, fxW1, fxb1, fxW2, fxb2, fxW3, fxb3,
                                    feW1, feb1, out, base1, bases);
    // ---- round 2 ----
    edge6_k<<<gE, thr, 0, stream>>>(base1, bases, sed, gcursor,
                                    feW2, feb2, feW3, feb3, mq);
    node5_k<<<gN, thr, 0, stream>>>(out, mq, fxW1, fxb1, fxW2, fxb2, fxW3, fxb3,
                                    feW1, feb1, out, base1, bases);
}

// Round 6
// 1248.794 us; speedup vs baseline: 1.0024x; 1.0024x over previous
//
#include <hip/hip_runtime.h>

// MsgPassingNN: 3 rounds of edge-MLP + segment_sum + node-MLP.
// N=100000 nodes (D=16), E=3200000 edges.
// fe: 32 -> 9 (relu) -> 9 (relu) -> 9 ; fx: 25 -> 9 (relu) -> 9 (relu) -> 16
//
// R8 structure (vs R6/R7):
//   * fe layer-3 HOISTED out of the edge loop (it is linear):
//       m_d = W3^T (sum_e h2_e) + deg_d * b3
//     Edge kernel sums h2 (9) + count (1) into a 128x10 LDS tile via
//     ds_add_f32; node kernel applies W3/b3. Edge = 9 adds + relu + 81 FMA
//     + relu + 10 LDS atomics. No scan, no W3, no global atomics.
//   * R7's spill bug fixed: ONE edge in flight (no A[4][9] staging), no
//     launch_bounds occupancy cap -> target <=64 VGPR, zero scratch.
//   * lsort_k deleted (tile reduction needs bucket grouping only; unsorted
//     order also spreads LDS-atomic addresses -> few collisions).
//   * 4 blocks/bucket (QPB=4, 2048 slots each, 8 strided slots/thread).
//     Full blocks take a branchless unrolled path (compiler pipelines the
//     independent gathers); the single partial block per bucket takes a
//     clamped/guarded path. Empty blocks zero-fill their partial planes.
//   * Flush = coalesced plane stores into 4 SoA partials mq[(q*10+j)*NN+n];
//     node sums them (40 coalesced loads). Zero atomics in all rounds.
//   * fe layer-1 stays hoisted per node (base1 = W1d^T x + b1, stride 12;
//     base_s = W1s^T x, stride 16 = one 64B line per random gather).

constexpr int NN = 100000;
constexpr int NE = 3200000;
constexpr int NBK = (NN + 127) / 128;      // 782 buckets of 128 nodes
constexpr int SLOT = 8192;                 // sed slots per bucket (avg fill 4096)
constexpr int EPB = 4096;                  // edges per bsort block (16/thread)
constexpr int NBLK_SORT = (NE + EPB - 1) / EPB;   // 782
constexpr int NB_NODE = (NN + 255) / 256;  // 391
constexpr int QPB = 4;                     // edge blocks (and partials) per bucket
constexpr int EPBLK = SLOT / QPB;          // 2048 slots per edge block
constexpr int IPT = EPBLK / 256;           // 8 strided slots per thread

// ---------------- bucket cursor init ----------------

__global__ __launch_bounds__(256) void init_k(int* __restrict__ gcursor)
{
    int i = blockIdx.x * 256 + threadIdx.x;
    if (i < NBK) gcursor[i] = i * SLOT;
}

// ---------------- one-pass bucket sort (dst>>7) ----------------

__global__ __launch_bounds__(256) void bsort_k(const int* __restrict__ src,
                                               const int* __restrict__ dst,
                                               int* __restrict__ gcursor,
                                               unsigned* __restrict__ sed)
{
    __shared__ int lhist[NBK];
    __shared__ int lbase[NBK];
    const int t = threadIdx.x;
    for (int i = t; i < NBK; i += 256) lhist[i] = 0;
    __syncthreads();

    const int blkbase = blockIdx.x * EPB;
    unsigned pr[16], sv[16];
    #pragma unroll
    for (int k = 0; k < 16; ++k) {
        const int e = blkbase + k * 256 + t;
        if (e < NE) {
            const int d = dst[e];
            const int s = src[e];
            const int bin = d >> 7;
            const int r = atomicAdd(&lhist[bin], 1);      // LDS atomic
            pr[k] = ((unsigned)bin << 13) | (unsigned)r;  // r < 4096 < 2^13
            sv[k] = ((unsigned)(d & 127) << 17) | (unsigned)s;
        } else {
            pr[k] = 0xFFFFFFFFu;
        }
    }
    __syncthreads();

    for (int i = t; i < NBK; i += 256) {
        const int c = lhist[i];
        if (c) lbase[i] = atomicAdd(&gcursor[i], c);      // 1 global atomic/(block,bin)
    }
    __syncthreads();

    #pragma unroll
    for (int k = 0; k < 16; ++k) {
        if (pr[k] != 0xFFFFFFFFu) {
            const int bin = (int)(pr[k] >> 13);
            const int r = (int)(pr[k] & 0x1FFFu);
            sed[lbase[bin] + r] = sv[k];
        }
    }
}

// ---------------- round-0 prologue: base1 + base_s from X0 ----------------

__global__ __launch_bounds__(256) void base_k(const float* __restrict__ X,
                                              const float* __restrict__ feW1,
                                              const float* __restrict__ feb1,
                                              float* __restrict__ base1,
                                              float* __restrict__ bases)
{
    __shared__ float sW[32 * 12], sb[9];
    const int t = threadIdx.x;
    for (int i = t; i < 288; i += 256) sW[(i / 9) * 12 + (i % 9)] = feW1[i];
    if (t < 9) sb[t] = feb1[t];
    __syncthreads();

    const int n = blockIdx.x * 256 + t;
    if (n >= NN) return;

    float x[16];
    const float4* p = reinterpret_cast<const float4*>(X + (size_t)n * 16);
    #pragma unroll
    for (int q = 0; q < 4; ++q) {
        float4 v = p[q];
        x[4*q] = v.x; x[4*q+1] = v.y; x[4*q+2] = v.z; x[4*q+3] = v.w;
    }
    float bd[9];
    #pragma unroll
    for (int j = 0; j < 9; ++j) bd[j] = sb[j];
    #pragma unroll
    for (int i = 0; i < 16; ++i) {
        const float xi = x[i];
        #pragma unroll
        for (int j = 0; j < 9; ++j) bd[j] = fmaf(xi, sW[i * 12 + j], bd[j]);
    }
    float bs[9];
    #pragma unroll
    for (int j = 0; j < 9; ++j) bs[j] = 0.f;
    #pragma unroll
    for (int i = 0; i < 16; ++i) {
        const float xi = x[i];
        #pragma unroll
        for (int j = 0; j < 9; ++j) bs[j] = fmaf(xi, sW[(16 + i) * 12 + j], bs[j]);
    }
    float* bp = base1 + (size_t)n * 12;
    #pragma unroll
    for (int j = 0; j < 9; ++j) bp[j] = bd[j];
    float* sp = bases + (size_t)n * 16;
    #pragma unroll
    for (int j = 0; j < 9; ++j) sp[j] = bs[j];
}

// ---------------- edge round: LDS h2-tile reduction ----------------

__global__ __launch_bounds__(256) void edge7_k(
    const float* __restrict__ base1,
    const float* __restrict__ bases,
    const unsigned* __restrict__ sed,
    const int* __restrict__ gcursor,
    const float* __restrict__ feW2, const float* __restrict__ feb2,
    float* __restrict__ mq)   // SoA partials: mq[(q*10+j)*NN + n], j in [0,10)
{
    const int t = threadIdx.x;
    const int b = blockIdx.x >> 2;          // bucket
    const int q = blockIdx.x & (QPB - 1);   // partial index
    const int nbase = b * 128;
    const int nn = (NN - nbase < 128) ? (NN - nbase) : 128;
    const int fill = gcursor[b] - b * SLOT;
    const int lo = q * EPBLK;

    if (lo >= fill) {
        // no edges for this partial: zero-fill its planes (coalesced), done
        for (int i = t; i < 128 * 10; i += 256) {
            const int dl = i & 127, j = i >> 7;
            if (dl < nn) mq[(size_t)(q * 10 + j) * NN + nbase + dl] = 0.f;
        }
        return;
    }

    __shared__ float sW2[9 * 12], sb2[9];
    __shared__ float b1l[128 * 12];   // base1 tile, float4-readable rows
    __shared__ float ml[128 * 10];    // h2-sum (9) + count (1) per node
    if (t < 81) sW2[(t / 9) * 12 + (t % 9)] = feW2[t];
    if (t >= 96 && t < 105) sb2[t - 96] = feb2[t - 96];
    for (int i = t; i < nn * 12; i += 256) b1l[i] = base1[(size_t)nbase * 12 + i];
    for (int i = t; i < 128 * 10; i += 256) ml[i] = 0.f;
    __syncthreads();

    const int cap = (fill < lo + EPBLK) ? fill : lo + EPBLK;

    // one edge in flight at a time (R7 spill lesson); gathers across the
    // unrolled iterations are independent -> compiler pipelines them.
    auto body = [&](unsigned pk, bool valid) {
        const int s  = (int)(pk & 0x1FFFFu);
        const int dl = (int)(pk >> 17);
        const float4* ps = reinterpret_cast<const float4*>(bases + (size_t)s * 16);
        const float4 c0 = ps[0], c1 = ps[1];
        const float c8 = bases[(size_t)s * 16 + 8];
        const float4* pb = reinterpret_cast<const float4*>(&b1l[dl * 12]);
        const float4 b0 = pb[0], b1v = pb[1];
        const float b8 = b1l[dl * 12 + 8];
        float a[9];
        a[0] = b0.x + c0.x; a[1] = b0.y + c0.y; a[2] = b0.z + c0.z; a[3] = b0.w + c0.w;
        a[4] = b1v.x + c1.x; a[5] = b1v.y + c1.y; a[6] = b1v.z + c1.z; a[7] = b1v.w + c1.w;
        a[8] = b8 + c8;
        #pragma unroll
        for (int j = 0; j < 9; ++j) a[j] = fmaxf(a[j], 0.f);

        float h2[9];
        #pragma unroll
        for (int j = 0; j < 9; ++j) h2[j] = sb2[j];
        #pragma unroll
        for (int i = 0; i < 9; ++i) {
            const float ai = a[i];
            #pragma unroll
            for (int j = 0; j < 9; ++j) h2[j] = fmaf(ai, sW2[i * 12 + j], h2[j]);
        }
        if (valid) {
            const int d10 = dl * 10;
            #pragma unroll
            for (int j = 0; j < 9; ++j) atomicAdd(&ml[d10 + j], fmaxf(h2[j], 0.f));
            atomicAdd(&ml[d10 + 9], 1.f);
        }
    };

    const unsigned* sb_ptr = sed + (size_t)b * SLOT;
    if (cap - lo == EPBLK) {
        // full block: branchless, fully unrolled -> pipelined gathers
        #pragma unroll
        for (int it = 0; it < IPT; ++it)
            body(sb_ptr[lo + it * 256 + t], true);
    } else {
        // the single partial block of this bucket: clamp invalid lanes to a
        // safe slot (lo < fill) and predicate only the LDS atomics
        #pragma unroll
        for (int it = 0; it < IPT; ++it) {
            const int sl = lo + it * 256 + t;
            const bool v = sl < cap;
            body(sb_ptr[v ? sl : lo], v);
        }
    }
    __syncthreads();

    // coalesced flush of this block's partial planes
    for (int i = t; i < 128 * 10; i += 256) {
        const int dl = i & 127, j = i >> 7;
        if (dl < nn) mq[(size_t)(q * 10 + j) * NN + nbase + dl] = ml[dl * 10 + j];
    }
}

// ---------------- node round: partials + W3/b3 + fx MLP + next bases ----------------

__global__ __launch_bounds__(256) void node6_k(
    const float* __restrict__ Xin, const float* __restrict__ mq,
    const float* __restrict__ fxW1, const float* __restrict__ fxb1,
    const float* __restrict__ fxW2, const float* __restrict__ fxb2,
    const float* __restrict__ fxW3, const float* __restrict__ fxb3,
    const float* __restrict__ feW1, const float* __restrict__ feb1,
    const float* __restrict__ feW3, const float* __restrict__ feb3,
    float* __restrict__ Xout, float* __restrict__ base1out,
    float* __restrict__ basesout)
{
    __shared__ float sU1[25 * 12], sU2[9 * 12], sU3[9 * 16];
    __shared__ float sW1d[16 * 12], sW1s[16 * 12], sW3[9 * 12];
    __shared__ float sNB[34], sEB1[9], sEB3[9];
    const int t = threadIdx.x;
    if (t < 225) sU1[(t / 9) * 12 + (t % 9)] = fxW1[t];
    if (t < 81)  sU2[(t / 9) * 12 + (t % 9)] = fxW2[t];
    if (t < 144) sU3[t] = fxW3[t];
    if (t < 144) sW1d[(t / 9) * 12 + (t % 9)] = feW1[t];
    if (t >= 112) { int i = t - 112; sW1s[(i / 9) * 12 + (i % 9)] = feW1[144 + i]; }
    if (t >= 16 && t < 97) { int i = t - 16; sW3[(i / 9) * 12 + (i % 9)] = feW3[i]; }
    if (t < 9) sNB[t] = fxb1[t];
    if (t >= 32 && t < 41) sNB[9 + (t - 32)] = fxb2[t - 32];
    if (t >= 64 && t < 80) sNB[18 + (t - 64)] = fxb3[t - 64];
    if (t >= 96 && t < 105) sEB1[t - 96] = feb1[t - 96];
    if (t >= 128 && t < 137) sEB3[t - 128] = feb3[t - 128];
    __syncthreads();

    const int n = blockIdx.x * 256 + t;
    if (n >= NN) return;

    float xr[16];
    {
        const float4* p = reinterpret_cast<const float4*>(Xin + (size_t)n * 16);
        #pragma unroll
        for (int q = 0; q < 4; ++q) {
            float4 v = p[q];
            xr[4*q] = v.x; xr[4*q+1] = v.y; xr[4*q+2] = v.z; xr[4*q+3] = v.w;
        }
    }
    // sum the QPB partials: S = sum h2, deg = count
    float S[9];
    float deg = 0.f;
    #pragma unroll
    for (int j = 0; j < 9; ++j) S[j] = 0.f;
    #pragma unroll
    for (int qq = 0; qq < QPB; ++qq) {
        #pragma unroll
        for (int j = 0; j < 9; ++j) S[j] += mq[(size_t)(qq * 10 + j) * NN + n];
        deg += mq[(size_t)(qq * 10 + 9) * NN + n];
    }
    // m = W3^T S + deg * b3   (fe layer-3, hoisted from the edge loop)
    float mm[9];
    #pragma unroll
    for (int j = 0; j < 9; ++j) mm[j] = deg * sEB3[j];
    #pragma unroll
    for (int i = 0; i < 9; ++i) {
        const float si = S[i];
        #pragma unroll
        for (int j = 0; j < 9; ++j) mm[j] = fmaf(si, sW3[i * 12 + j], mm[j]);
    }

    float h1[9];
    #pragma unroll
    for (int j = 0; j < 9; ++j) h1[j] = sNB[j];
    #pragma unroll
    for (int i = 0; i < 16; ++i) {
        const float xi = xr[i];
        #pragma unroll
        for (int j = 0; j < 9; ++j) h1[j] = fmaf(xi, sU1[i * 12 + j], h1[j]);
    }
    #pragma unroll
    for (int i = 0; i < 9; ++i) {
        const float xi = mm[i];
        #pragma unroll
        for (int j = 0; j < 9; ++j) h1[j] = fmaf(xi, sU1[(16 + i) * 12 + j], h1[j]);
    }
    #pragma unroll
    for (int j = 0; j < 9; ++j) h1[j] = fmaxf(h1[j], 0.f);

    float h2[9];
    #pragma unroll
    for (int j = 0; j < 9; ++j) h2[j] = sNB[9 + j];
    #pragma unroll
    for (int i = 0; i < 9; ++i) {
        const float xi = h1[i];
        #pragma unroll
        for (int j = 0; j < 9; ++j) h2[j] = fmaf(xi, sU2[i * 12 + j], h2[j]);
    }
    #pragma unroll
    for (int j = 0; j < 9; ++j) h2[j] = fmaxf(h2[j], 0.f);

    float o[16];
    #pragma unroll
    for (int k = 0; k < 16; ++k) o[k] = sNB[18 + k];
    #pragma unroll
    for (int j = 0; j < 9; ++j) {
        const float hj = h2[j];
        #pragma unroll
        for (int k = 0; k < 16; ++k) o[k] = fmaf(hj, sU3[j * 16 + k], o[k]);
    }

    float4* po = reinterpret_cast<float4*>(Xout + (size_t)n * 16);
    #pragma unroll
    for (int q = 0; q < 4; ++q) {
        float4 v;
        v.x = o[4*q]; v.y = o[4*q+1]; v.z = o[4*q+2]; v.w = o[4*q+3];
        po[q] = v;
    }

    // base1 / base_s for NEXT round's edge kernel
    float bb[9];
    #pragma unroll
    for (int j = 0; j < 9; ++j) bb[j] = sEB1[j];
    #pragma unroll
    for (int i = 0; i < 16; ++i) {
        const float xi = o[i];
        #pragma unroll
        for (int j = 0; j < 9; ++j) bb[j] = fmaf(xi, sW1d[i * 12 + j], bb[j]);
    }
    float* bp = base1out + (size_t)n * 12;
    #pragma unroll
    for (int j = 0; j < 9; ++j) bp[j] = bb[j];

    float cc[9];
    #pragma unroll
    for (int j = 0; j < 9; ++j) cc[j] = 0.f;
    #pragma unroll
    for (int i = 0; i < 16; ++i) {
        const float xi = o[i];
        #pragma unroll
        for (int j = 0; j < 9; ++j) cc[j] = fmaf(xi, sW1s[i * 12 + j], cc[j]);
    }
    float* sp = basesout + (size_t)n * 16;
    #pragma unroll
    for (int j = 0; j < 9; ++j) sp[j] = cc[j];
}

extern "C" void kernel_launch(void* const* d_in, const int* in_sizes, int n_in,
                              void* d_out, int out_size, void* d_ws, size_t ws_size,
                              hipStream_t stream)
{
    (void)in_sizes; (void)n_in; (void)out_size; (void)ws_size;
    const float* X0   = (const float*)d_in[0];
    const int*   esrc = (const int*)d_in[1];
    const int*   edst = (const int*)d_in[2];
    const float* feW1 = (const float*)d_in[3];
    const float* feb1 = (const float*)d_in[4];
    const float* feW2 = (const float*)d_in[5];
    const float* feb2 = (const float*)d_in[6];
    const float* feW3 = (const float*)d_in[7];
    const float* feb3 = (const float*)d_in[8];
    const float* fxW1 = (const float*)d_in[9];
    const float* fxb1 = (const float*)d_in[10];
    const float* fxW2 = (const float*)d_in[11];
    const float* fxb2 = (const float*)d_in[12];
    const float* fxW3 = (const float*)d_in[13];
    const float* fxb3 = (const float*)d_in[14];
    float* out = (float*)d_out;

    // workspace layout (floats unless noted). total ~53 MB.
    float* base1  = (float*)d_ws;                          // NN*12
    float* bases  = base1 + (size_t)NN * 12;               // NN*16 (64B rows)
    float* mq     = bases + (size_t)NN * 16;               // QPB*10*NN SoA partials
    int* gcursor  = (int*)(mq + (size_t)QPB * 10 * NN);    // NBK (padded to 1024)
    unsigned* sed = (unsigned*)(gcursor + 1024);           // NBK*SLOT u32 = 25.6MB

    const dim3 thr(256);
    const dim3 gS(NBLK_SORT);          // 782
    const dim3 gE(NBK * QPB);          // 3128
    const dim3 gN(NB_NODE);            // 391

    // ---- bucket sort (once per launch) ----
    init_k<<<4, thr, 0, stream>>>(gcursor);
    bsort_k<<<gS, thr, 0, stream>>>(esrc, edst, gcursor, sed);

    // ---- round 0 ----
    base_k<<<gN, thr, 0, stream>>>(X0, feW1, feb1, base1, bases);
    edge7_k<<<gE, thr, 0, stream>>>(base1, bases, sed, gcursor, feW2, feb2, mq);
    node6_k<<<gN, thr, 0, stream>>>(X0, mq, fxW1, fxb1, fxW2, fxb2, fxW3, fxb3,
                                    feW1, feb1, feW3, feb3, out, base1, bases);
    // ---- round 1 (node updates out in place; edge never reads X) ----
    edge7_k<<<gE, thr, 0, stream>>>(base1, bases, sed, gcursor, feW2, feb2, mq);
    node6_k<<<gN, thr, 0, stream>>>(out, mq, fxW1, fxb1, fxW2, fxb2, fxW3, fxb3,
                                    feW1, feb1, feW3, feb3, out, base1, bases);
    // ---- round 2 ----
    edge7_k<<<gE, thr, 0, stream>>>(base1, bases, sed, gcursor, feW2, feb2, mq);
    node6_k<<<gN, thr, 0, stream>>>(out, mq, fxW1, fxb1, fxW2, fxb2, fxW3, fxb3,
                                    feW1, feb1, feW3, feb3, out, base1, bases);
}

// Round 7
// 554.684 us; speedup vs baseline: 2.2567x; 2.2514x over previous
//
#include <hip/hip_runtime.h>

// MsgPassingNN: 3 rounds of edge-MLP + segment_sum + node-MLP.
// N=100000 nodes (D=16), E=3200000 edges.
// fe: 32 -> 9 (relu) -> 9 (relu) -> 9 ; fx: 25 -> 9 (relu) -> 9 (relu) -> 16
//
// R9 = R6 (best verified: 559us) + fe layer-3 hoist + free segment counts.
//   * Two-level full dst-sort:
//       bsort_k: bucket = dst>>7 (782 buckets, 8192-slot slack regions),
//                LDS-histogram ranks + 1 global atomic/(block,bin).
//                gcursor holds per-bucket COUNTS (init via memset 0).
//       lsort_k: per-bucket LDS counting sort by d_local (in place).
//   * edge8_k: 1 thread/edge, 256-thr blocks (~36 VGPR, high occupancy),
//     wave-segmented scan of relu(h2) (ballot/clz distance-to-head);
//     tails atomicAdd 9 h2-sums + segment count (= dist+1, free from the
//     ballot mask). fe layer-3 is NOT in the edge loop (it is linear):
//       m_d = W3^T (sum relu(h2)) + deg_d * b3   (applied in node kernel)
//   * fe layer-1 hoisted per node: base1 = W1d^T x + b1 (stride 12),
//     base_s = W1s^T x (stride 16 = one 64B line per random gather).
//     Edge MLP = 9 adds + relu + 81 FMA + relu.
//   * node7_k: reads m (9 sums + deg), zeroes it for the next round,
//     applies W3/b3, fx MLP, writes out in place, recomputes base1/base_s.

constexpr int NN = 100000;
constexpr int NE = 3200000;
constexpr int NBK = (NN + 127) / 128;      // 782 buckets of 128 nodes
constexpr int SLOT = 8192;                 // sed slots per bucket (avg fill 4096)
constexpr int EPB = 4096;                  // edges per bsort block (16/thread)
constexpr int NBLK_SORT = (NE + EPB - 1) / EPB;   // 782
constexpr int NB_NODE = (NN + 255) / 256;  // 391

// ---------------- pass 1: bucket sort (dst>>7) ----------------
// gcursor[bin] = running count (memset to 0 before launch)

__global__ __launch_bounds__(256) void bsort_k(const int* __restrict__ src,
                                               const int* __restrict__ dst,
                                               int* __restrict__ gcursor,
                                               unsigned* __restrict__ sed)
{
    __shared__ int lhist[NBK];
    __shared__ int lbase[NBK];
    const int t = threadIdx.x;
    for (int i = t; i < NBK; i += 256) lhist[i] = 0;
    __syncthreads();

    const int blkbase = blockIdx.x * EPB;
    unsigned pr[16], sv[16];
    #pragma unroll
    for (int k = 0; k < 16; ++k) {
        const int e = blkbase + k * 256 + t;
        if (e < NE) {
            const int d = dst[e];
            const int s = src[e];
            const int bin = d >> 7;
            const int r = atomicAdd(&lhist[bin], 1);      // LDS atomic
            pr[k] = ((unsigned)bin << 13) | (unsigned)r;  // r < 4096 < 2^13
            sv[k] = ((unsigned)(d & 127) << 17) | (unsigned)s;
        } else {
            pr[k] = 0xFFFFFFFFu;
        }
    }
    __syncthreads();

    for (int i = t; i < NBK; i += 256) {
        const int c = lhist[i];
        if (c) lbase[i] = atomicAdd(&gcursor[i], c);      // offset within bucket
    }
    __syncthreads();

    #pragma unroll
    for (int k = 0; k < 16; ++k) {
        if (pr[k] != 0xFFFFFFFFu) {
            const int bin = (int)(pr[k] >> 13);
            const int r = (int)(pr[k] & 0x1FFFu);
            sed[(size_t)bin * SLOT + lbase[bin] + r] = sv[k];
        }
    }
}

// ---------------- pass 2: in-bucket counting sort by d_local (in place) ----------------

__global__ __launch_bounds__(512) void lsort_k(unsigned* __restrict__ sed,
                                               const int* __restrict__ gcursor)
{
    __shared__ unsigned buf[SLOT];    // 32 KB
    __shared__ unsigned obuf[SLOT];   // 32 KB
    __shared__ int hist[128];
    __shared__ int cur[128];
    const int t = threadIdx.x;
    const int b = blockIdx.x;
    const int base = b * SLOT;
    int fill = gcursor[b];
    if (fill > SLOT) fill = SLOT;     // safety clamp (never hit for this input)

    if (t < 128) hist[t] = 0;
    __syncthreads();
    for (int i = t; i < fill; i += 512) {
        unsigned v = sed[base + i];
        buf[i] = v;
        atomicAdd(&hist[v >> 17], 1);
    }
    __syncthreads();
    // exclusive scan of 128 bins (Hillis-Steele in LDS)
    if (t < 128) cur[t] = hist[t];
    __syncthreads();
    for (int off = 1; off < 128; off <<= 1) {
        int a = (t < 128 && t >= off) ? cur[t - off] : 0;
        __syncthreads();
        if (t < 128) cur[t] += a;
        __syncthreads();
    }
    if (t < 128) cur[t] -= hist[t];   // exclusive prefix
    __syncthreads();
    for (int i = t; i < fill; i += 512) {
        unsigned v = buf[i];
        int r = atomicAdd(&cur[v >> 17], 1);
        obuf[r] = v;
    }
    __syncthreads();
    for (int i = t; i < fill; i += 512) sed[base + i] = obuf[i];
}

// ---------------- round-0 prologue: base1 + base_s from X0, zero m ----------------

__global__ __launch_bounds__(256) void base_k(const float* __restrict__ X,
                                              const float* __restrict__ feW1,
                                              const float* __restrict__ feb1,
                                              float* __restrict__ base1,
                                              float* __restrict__ bases,
                                              float* __restrict__ m)
{
    __shared__ float sW[32 * 12], sb[9];
    const int t = threadIdx.x;
    for (int i = t; i < 288; i += 256) sW[(i / 9) * 12 + (i % 9)] = feW1[i];
    if (t < 9) sb[t] = feb1[t];
    __syncthreads();

    const int n = blockIdx.x * 256 + t;
    if (n >= NN) return;

    float x[16];
    const float4* p = reinterpret_cast<const float4*>(X + (size_t)n * 16);
    #pragma unroll
    for (int q = 0; q < 4; ++q) {
        float4 v = p[q];
        x[4*q] = v.x; x[4*q+1] = v.y; x[4*q+2] = v.z; x[4*q+3] = v.w;
    }
    float bd[9];
    #pragma unroll
    for (int j = 0; j < 9; ++j) bd[j] = sb[j];
    #pragma unroll
    for (int i = 0; i < 16; ++i) {
        const float xi = x[i];
        #pragma unroll
        for (int j = 0; j < 9; ++j) bd[j] = fmaf(xi, sW[i * 12 + j], bd[j]);
    }
    float bs[9];
    #pragma unroll
    for (int j = 0; j < 9; ++j) bs[j] = 0.f;
    #pragma unroll
    for (int i = 0; i < 16; ++i) {
        const float xi = x[i];
        #pragma unroll
        for (int j = 0; j < 9; ++j) bs[j] = fmaf(xi, sW[(16 + i) * 12 + j], bs[j]);
    }
    float* bp = base1 + (size_t)n * 12;
    #pragma unroll
    for (int j = 0; j < 9; ++j) bp[j] = bd[j];
    float* sp = bases + (size_t)n * 16;
    #pragma unroll
    for (int j = 0; j < 9; ++j) sp[j] = bs[j];
    float* mp = m + (size_t)n * 10;
    #pragma unroll
    for (int j = 0; j < 10; ++j) mp[j] = 0.f;
}

// ---------------- edge round: 1 thread / sorted slot, wave scan of h2 ----------------

__global__ __launch_bounds__(256) void edge8_k(
    const float* __restrict__ base1,
    const float* __restrict__ bases,
    const unsigned* __restrict__ sed,
    const int* __restrict__ gcursor,
    const float* __restrict__ feW2, const float* __restrict__ feb2,
    float* __restrict__ m)    // NN x 10: 9 h2-sums + deg
{
    const int t = threadIdx.x;
    const int b = blockIdx.x >> 5;                 // bucket (SLOT/256 = 32 blocks/bucket)
    const int idx0 = (blockIdx.x & 31) * 256;      // slot offset within bucket
    const int fill = gcursor[b];
    if (idx0 >= fill) return;                      // block-uniform early exit

    __shared__ float sW2[9 * 12], sb2[9];
    if (t < 81)  sW2[(t / 9) * 12 + (t % 9)] = feW2[t];
    if (t >= 96 && t < 105) sb2[t - 96] = feb2[t - 96];
    __syncthreads();

    const int idx = idx0 + t;
    const bool valid = idx < fill;
    const int lane = t & 63;
    if (__ballot(valid) == 0ull) return;           // wave fully past fill

    int dl;
    float o[9];
    if (valid) {
        const unsigned pk = sed[(size_t)b * SLOT + idx];
        dl = (int)(pk >> 17);
        const int s = (int)(pk & 0x1FFFFu);

        // h1 = relu(base1[d] + base_s[s]); consecutive lanes share d -> L1 hits
        float a[9];
        {
            const float4* pb = reinterpret_cast<const float4*>(base1 + (size_t)(b * 128 + dl) * 12);
            float4 b0 = pb[0], b1 = pb[1];
            const float b8 = base1[(size_t)(b * 128 + dl) * 12 + 8];
            const float4* ps = reinterpret_cast<const float4*>(bases + (size_t)s * 16);
            float4 c0 = ps[0], c1 = ps[1];
            const float c8 = bases[(size_t)s * 16 + 8];
            a[0] = b0.x + c0.x; a[1] = b0.y + c0.y; a[2] = b0.z + c0.z; a[3] = b0.w + c0.w;
            a[4] = b1.x + c1.x; a[5] = b1.y + c1.y; a[6] = b1.z + c1.z; a[7] = b1.w + c1.w;
            a[8] = b8 + c8;
        }
        #pragma unroll
        for (int j = 0; j < 9; ++j) a[j] = fmaxf(a[j], 0.f);

        // h2 = relu(W2^T a + b2); layer 3 is hoisted to the node kernel
        #pragma unroll
        for (int j = 0; j < 9; ++j) o[j] = sb2[j];
        #pragma unroll
        for (int i = 0; i < 9; ++i) {
            const float ai = a[i];
            #pragma unroll
            for (int j = 0; j < 9; ++j) o[j] = fmaf(ai, sW2[i * 12 + j], o[j]);
        }
        #pragma unroll
        for (int j = 0; j < 9; ++j) o[j] = fmaxf(o[j], 0.f);
    } else {
        dl = 128 + lane;                            // unique sentinel: own segment
        #pragma unroll
        for (int j = 0; j < 9; ++j) o[j] = 0.f;
    }

    // segmented inclusive scan by dl over the 64-lane wave (dl sorted)
    const int dprev = __shfl_up(dl, 1);
    const bool head = (lane == 0) || (dprev != dl);
    const unsigned long long hm = __ballot(head);
    const int dist = __clzll((long long)(hm << (63 - lane)));  // 0 if head
    #pragma unroll
    for (int off = 1; off < 64; off <<= 1) {
        const bool ok = (dist >= off);
        #pragma unroll
        for (int j = 0; j < 9; ++j) {
            const float ov = __shfl_up(o[j], off);
            o[j] += ok ? ov : 0.f;
        }
    }
    const bool tail = (lane == 63) || (((hm >> (lane + 1)) & 1ull) != 0ull);
    if (tail && valid) {                            // segment tail -> global m
        float* mp = m + (size_t)(b * 128 + dl) * 10;
        #pragma unroll
        for (int j = 0; j < 9; ++j) atomicAdd(mp + j, o[j]);
        atomicAdd(mp + 9, (float)(dist + 1));       // segment length = free count
    }
}

// ---------------- node round: W3/b3 + fx MLP + zero m + next bases ----------------

__global__ __launch_bounds__(256) void node7_k(
    const float* __restrict__ Xin, float* __restrict__ m,
    const float* __restrict__ fxW1, const float* __restrict__ fxb1,
    const float* __restrict__ fxW2, const float* __restrict__ fxb2,
    const float* __restrict__ fxW3, const float* __restrict__ fxb3,
    const float* __restrict__ feW1, const float* __restrict__ feb1,
    const float* __restrict__ feW3, const float* __restrict__ feb3,
    float* __restrict__ Xout, float* __restrict__ base1out,
    float* __restrict__ basesout)
{
    __shared__ float sU1[25 * 12], sU2[9 * 12], sU3[9 * 16];
    __shared__ float sW1d[16 * 12], sW1s[16 * 12], sW3[9 * 12];
    __shared__ float sNB[34], sEB1[9], sEB3[9];
    const int t = threadIdx.x;
    if (t < 225) sU1[(t / 9) * 12 + (t % 9)] = fxW1[t];
    if (t < 81)  sU2[(t / 9) * 12 + (t % 9)] = fxW2[t];
    if (t < 144) sU3[t] = fxW3[t];
    if (t < 144) sW1d[(t / 9) * 12 + (t % 9)] = feW1[t];
    if (t >= 112) { int i = t - 112; sW1s[(i / 9) * 12 + (i % 9)] = feW1[144 + i]; }
    if (t >= 16 && t < 97) { int i = t - 16; sW3[(i / 9) * 12 + (i % 9)] = feW3[i]; }
    if (t < 9) sNB[t] = fxb1[t];
    if (t >= 32 && t < 41) sNB[9 + (t - 32)] = fxb2[t - 32];
    if (t >= 64 && t < 80) sNB[18 + (t - 64)] = fxb3[t - 64];
    if (t >= 96 && t < 105) sEB1[t - 96] = feb1[t - 96];
    if (t >= 128 && t < 137) sEB3[t - 128] = feb3[t - 128];
    __syncthreads();

    const int n = blockIdx.x * 256 + t;
    if (n >= NN) return;

    float xr[16];
    {
        const float4* p = reinterpret_cast<const float4*>(Xin + (size_t)n * 16);
        #pragma unroll
        for (int q = 0; q < 4; ++q) {
            float4 v = p[q];
            xr[4*q] = v.x; xr[4*q+1] = v.y; xr[4*q+2] = v.z; xr[4*q+3] = v.w;
        }
    }
    float S[9], deg;
    float* mp = m + (size_t)n * 10;
    #pragma unroll
    for (int j = 0; j < 9; ++j) S[j] = mp[j];
    deg = mp[9];
    #pragma unroll
    for (int j = 0; j < 10; ++j) mp[j] = 0.f;    // ready for next round

    // m = W3^T S + deg * b3   (fe layer-3, hoisted from the edge loop)
    float mm[9];
    #pragma unroll
    for (int j = 0; j < 9; ++j) mm[j] = deg * sEB3[j];
    #pragma unroll
    for (int i = 0; i < 9; ++i) {
        const float si = S[i];
        #pragma unroll
        for (int j = 0; j < 9; ++j) mm[j] = fmaf(si, sW3[i * 12 + j], mm[j]);
    }

    float h1[9];
    #pragma unroll
    for (int j = 0; j < 9; ++j) h1[j] = sNB[j];
    #pragma unroll
    for (int i = 0; i < 16; ++i) {
        const float xi = xr[i];
        #pragma unroll
        for (int j = 0; j < 9; ++j) h1[j] = fmaf(xi, sU1[i * 12 + j], h1[j]);
    }
    #pragma unroll
    for (int i = 0; i < 9; ++i) {
        const float xi = mm[i];
        #pragma unroll
        for (int j = 0; j < 9; ++j) h1[j] = fmaf(xi, sU1[(16 + i) * 12 + j], h1[j]);
    }
    #pragma unroll
    for (int j = 0; j < 9; ++j) h1[j] = fmaxf(h1[j], 0.f);

    float h2[9];
    #pragma unroll
    for (int j = 0; j < 9; ++j) h2[j] = sNB[9 + j];
    #pragma unroll
    for (int i = 0; i < 9; ++i) {
        const float xi = h1[i];
        #pragma unroll
        for (int j = 0; j < 9; ++j) h2[j] = fmaf(xi, sU2[i * 12 + j], h2[j]);
    }
    #pragma unroll
    for (int j = 0; j < 9; ++j) h2[j] = fmaxf(h2[j], 0.f);

    float o[16];
    #pragma unroll
    for (int k = 0; k < 16; ++k) o[k] = sNB[18 + k];
    #pragma unroll
    for (int j = 0; j < 9; ++j) {
        const float hj = h2[j];
        #pragma unroll
        for (int k = 0; k < 16; ++k) o[k] = fmaf(hj, sU3[j * 16 + k], o[k]);
    }

    float4* po = reinterpret_cast<float4*>(Xout + (size_t)n * 16);
    #pragma unroll
    for (int q = 0; q < 4; ++q) {
        float4 v;
        v.x = o[4*q]; v.y = o[4*q+1]; v.z = o[4*q+2]; v.w = o[4*q+3];
        po[q] = v;
    }

    // base1 / base_s for NEXT round's edge kernel
    float bb[9];
    #pragma unroll
    for (int j = 0; j < 9; ++j) bb[j] = sEB1[j];
    #pragma unroll
    for (int i = 0; i < 16; ++i) {
        const float xi = o[i];
        #pragma unroll
        for (int j = 0; j < 9; ++j) bb[j] = fmaf(xi, sW1d[i * 12 + j], bb[j]);
    }
    float* bp = base1out + (size_t)n * 12;
    #pragma unroll
    for (int j = 0; j < 9; ++j) bp[j] = bb[j];

    float cc[9];
    #pragma unroll
    for (int j = 0; j < 9; ++j) cc[j] = 0.f;
    #pragma unroll
    for (int i = 0; i < 16; ++i) {
        const float xi = o[i];
        #pragma unroll
        for (int j = 0; j < 9; ++j) cc[j] = fmaf(xi, sW1s[i * 12 + j], cc[j]);
    }
    float* sp = basesout + (size_t)n * 16;
    #pragma unroll
    for (int j = 0; j < 9; ++j) sp[j] = cc[j];
}

extern "C" void kernel_launch(void* const* d_in, const int* in_sizes, int n_in,
                              void* d_out, int out_size, void* d_ws, size_t ws_size,
                              hipStream_t stream)
{
    (void)in_sizes; (void)n_in; (void)out_size; (void)ws_size;
    const float* X0   = (const float*)d_in[0];
    const int*   esrc = (const int*)d_in[1];
    const int*   edst = (const int*)d_in[2];
    const float* feW1 = (const float*)d_in[3];
    const float* feb1 = (const float*)d_in[4];
    const float* feW2 = (const float*)d_in[5];
    const float* feb2 = (const float*)d_in[6];
    const float* feW3 = (const float*)d_in[7];
    const float* feb3 = (const float*)d_in[8];
    const float* fxW1 = (const float*)d_in[9];
    const float* fxb1 = (const float*)d_in[10];
    const float* fxW2 = (const float*)d_in[11];
    const float* fxb2 = (const float*)d_in[12];
    const float* fxW3 = (const float*)d_in[13];
    const float* fxb3 = (const float*)d_in[14];
    float* out = (float*)d_out;

    // workspace layout (floats unless noted). total ~41 MB.
    float* base1  = (float*)d_ws;                         // NN*12
    float* bases  = base1 + (size_t)NN * 12;              // NN*16 (64B rows)
    float* mb     = bases + (size_t)NN * 16;              // NN*10 (9 sums + deg)
    int* gcursor  = (int*)(mb + (size_t)NN * 10);         // NBK (padded to 1024)
    unsigned* sed = (unsigned*)(gcursor + 1024);          // NBK*SLOT u32 = 25.6MB

    const dim3 thr(256);
    const dim3 gS(NBLK_SORT);          // 782
    const dim3 gL(NBK);                // 782
    const dim3 gE(NBK * (SLOT / 256)); // 25024
    const dim3 gN(NB_NODE);            // 391

    // ---- two-level sort (once per launch) ----
    hipMemsetAsync(gcursor, 0, NBK * sizeof(int), stream);
    bsort_k<<<gS, thr, 0, stream>>>(esrc, edst, gcursor, sed);
    lsort_k<<<gL, dim3(512), 0, stream>>>(sed, gcursor);

    // ---- round 0 ----
    base_k<<<gN, thr, 0, stream>>>(X0, feW1, feb1, base1, bases, mb);
    edge8_k<<<gE, thr, 0, stream>>>(base1, bases, sed, gcursor, feW2, feb2, mb);
    node7_k<<<gN, thr, 0, stream>>>(X0, mb, fxW1, fxb1, fxW2, fxb2, fxW3, fxb3,
                                    feW1, feb1, feW3, feb3, out, base1, bases);
    // ---- round 1 (node updates out in place; edge never reads X) ----
    edge8_k<<<gE, thr, 0, stream>>>(base1, bases, sed, gcursor, feW2, feb2, mb);
    node7_k<<<gN, thr, 0, stream>>>(out, mb, fxW1, fxb1, fxW2, fxb2, fxW3, fxb3,
                                    feW1, feb1, feW3, feb3, out, base1, bases);
    // ---- round 2 ----
    edge8_k<<<gE, thr, 0, stream>>>(base1, bases, sed, gcursor, feW2, feb2, mb);
    node7_k<<<gN, thr, 0, stream>>>(out, mb, fxW1, fxb1, fxW2, fxb2, fxW3, fxb3,
                                    feW1, feb1, feW3, feb3, out, base1, bases);
}

// Round 8
// 492.394 us; speedup vs baseline: 2.5422x; 1.1265x over previous
//
#include <hip/hip_runtime.h>

// MsgPassingNN: 3 rounds of edge-MLP + segment_sum + node-MLP.
// N=100000 nodes (D=16), E=3200000 edges.
// fe: 32 -> 9 (relu) -> 9 (relu) -> 9 ; fx: 25 -> 9 (relu) -> 9 (relu) -> 16
//
// R10 = R9 (554.7us) + de-LDS of all wave-uniform weights.
//   * Theory: edge kernel is DS-pipe-bound (~144 DS ops/wave: 90 LDS weight
//     reads + 54 scan bpermutes). Weights are wave-uniform -> read them
//     DIRECTLY from global with kernel-arg-uniform addresses so the backend
//     scalarizes to s_load (constant cache, scalar pipe). LDS + barrier
//     removed from edge & node kernels entirely.
//   * Edge kernel made fully branchless so weight loads sit in uniform
//     control flow: invalid lanes clamp slot to fill-1 (a real edge),
//     take sentinel dl=128+lane (own segment, garbage stays in-lane),
//     only the tail atomic is predicated.
//   * Everything else identical to R9: two-level sort (bsort bucket=dst>>7,
//     lsort in-bucket counting sort), fe layer-1 hoisted per node
//     (base1 = W1d^T x + b1 stride 12; base_s = W1s^T x stride 16),
//     fe layer-3 hoisted to node kernel (m = W3^T sum relu(h2) + deg*b3,
//     deg = segment length from the ballot mask), wave-segmented scan,
//     node writes out in place.

constexpr int NN = 100000;
constexpr int NE = 3200000;
constexpr int NBK = (NN + 127) / 128;      // 782 buckets of 128 nodes
constexpr int SLOT = 8192;                 // sed slots per bucket (avg fill 4096)
constexpr int EPB = 4096;                  // edges per bsort block (16/thread)
constexpr int NBLK_SORT = (NE + EPB - 1) / EPB;   // 782
constexpr int NB_NODE = (NN + 255) / 256;  // 391

// ---------------- pass 1: bucket sort (dst>>7) ----------------
// gcursor[bin] = running count (memset to 0 before launch)

__global__ __launch_bounds__(256) void bsort_k(const int* __restrict__ src,
                                               const int* __restrict__ dst,
                                               int* __restrict__ gcursor,
                                               unsigned* __restrict__ sed)
{
    __shared__ int lhist[NBK];
    __shared__ int lbase[NBK];
    const int t = threadIdx.x;
    for (int i = t; i < NBK; i += 256) lhist[i] = 0;
    __syncthreads();

    const int blkbase = blockIdx.x * EPB;
    unsigned pr[16], sv[16];
    #pragma unroll
    for (int k = 0; k < 16; ++k) {
        const int e = blkbase + k * 256 + t;
        if (e < NE) {
            const int d = dst[e];
            const int s = src[e];
            const int bin = d >> 7;
            const int r = atomicAdd(&lhist[bin], 1);      // LDS atomic
            pr[k] = ((unsigned)bin << 13) | (unsigned)r;  // r < 4096 < 2^13
            sv[k] = ((unsigned)(d & 127) << 17) | (unsigned)s;
        } else {
            pr[k] = 0xFFFFFFFFu;
        }
    }
    __syncthreads();

    for (int i = t; i < NBK; i += 256) {
        const int c = lhist[i];
        if (c) lbase[i] = atomicAdd(&gcursor[i], c);      // offset within bucket
    }
    __syncthreads();

    #pragma unroll
    for (int k = 0; k < 16; ++k) {
        if (pr[k] != 0xFFFFFFFFu) {
            const int bin = (int)(pr[k] >> 13);
            const int r = (int)(pr[k] & 0x1FFFu);
            sed[(size_t)bin * SLOT + lbase[bin] + r] = sv[k];
        }
    }
}

// ---------------- pass 2: in-bucket counting sort by d_local (in place) ----------------

__global__ __launch_bounds__(512) void lsort_k(unsigned* __restrict__ sed,
                                               const int* __restrict__ gcursor)
{
    __shared__ unsigned buf[SLOT];    // 32 KB
    __shared__ unsigned obuf[SLOT];   // 32 KB
    __shared__ int hist[128];
    __shared__ int cur[128];
    const int t = threadIdx.x;
    const int b = blockIdx.x;
    const int base = b * SLOT;
    int fill = gcursor[b];
    if (fill > SLOT) fill = SLOT;     // safety clamp (never hit for this input)

    if (t < 128) hist[t] = 0;
    __syncthreads();
    for (int i = t; i < fill; i += 512) {
        unsigned v = sed[base + i];
        buf[i] = v;
        atomicAdd(&hist[v >> 17], 1);
    }
    __syncthreads();
    // exclusive scan of 128 bins (Hillis-Steele in LDS)
    if (t < 128) cur[t] = hist[t];
    __syncthreads();
    for (int off = 1; off < 128; off <<= 1) {
        int a = (t < 128 && t >= off) ? cur[t - off] : 0;
        __syncthreads();
        if (t < 128) cur[t] += a;
        __syncthreads();
    }
    if (t < 128) cur[t] -= hist[t];   // exclusive prefix
    __syncthreads();
    for (int i = t; i < fill; i += 512) {
        unsigned v = buf[i];
        int r = atomicAdd(&cur[v >> 17], 1);
        obuf[r] = v;
    }
    __syncthreads();
    for (int i = t; i < fill; i += 512) sed[base + i] = obuf[i];
}

// ---------------- round-0 prologue: base1 + base_s from X0, zero m ----------------

__global__ __launch_bounds__(256) void base_k(const float* __restrict__ X,
                                              const float* __restrict__ feW1,
                                              const float* __restrict__ feb1,
                                              float* __restrict__ base1,
                                              float* __restrict__ bases,
                                              float* __restrict__ m)
{
    const int n = blockIdx.x * 256 + threadIdx.x;
    if (n >= NN) return;

    float x[16];
    const float4* p = reinterpret_cast<const float4*>(X + (size_t)n * 16);
    #pragma unroll
    for (int q = 0; q < 4; ++q) {
        float4 v = p[q];
        x[4*q] = v.x; x[4*q+1] = v.y; x[4*q+2] = v.z; x[4*q+3] = v.w;
    }
    float bd[9];
    #pragma unroll
    for (int j = 0; j < 9; ++j) bd[j] = feb1[j];
    #pragma unroll
    for (int i = 0; i < 16; ++i) {
        const float xi = x[i];
        #pragma unroll
        for (int j = 0; j < 9; ++j) bd[j] = fmaf(xi, feW1[i * 9 + j], bd[j]);
    }
    float bs[9];
    #pragma unroll
    for (int j = 0; j < 9; ++j) bs[j] = 0.f;
    #pragma unroll
    for (int i = 0; i < 16; ++i) {
        const float xi = x[i];
        #pragma unroll
        for (int j = 0; j < 9; ++j) bs[j] = fmaf(xi, feW1[(16 + i) * 9 + j], bs[j]);
    }
    float* bp = base1 + (size_t)n * 12;
    #pragma unroll
    for (int j = 0; j < 9; ++j) bp[j] = bd[j];
    float* sp = bases + (size_t)n * 16;
    #pragma unroll
    for (int j = 0; j < 9; ++j) sp[j] = bs[j];
    float* mp = m + (size_t)n * 10;
    #pragma unroll
    for (int j = 0; j < 10; ++j) mp[j] = 0.f;
}

// ---------------- edge round: 1 thread / sorted slot, wave scan of h2 ----------------
// No LDS, no barrier: weights read directly (uniform address -> s_load).

__global__ __launch_bounds__(256) void edge9_k(
    const float* __restrict__ base1,
    const float* __restrict__ bases,
    const unsigned* __restrict__ sed,
    const int* __restrict__ gcursor,
    const float* __restrict__ feW2, const float* __restrict__ feb2,
    float* __restrict__ m)    // NN x 10: 9 h2-sums + deg
{
    const int t = threadIdx.x;
    const int b = blockIdx.x >> 5;                 // bucket (SLOT/256 = 32 blocks/bucket)
    const int idx0 = (blockIdx.x & 31) * 256;      // slot offset within bucket
    const int fill = gcursor[b];
    if (idx0 >= fill) return;                      // uniform early exit

    const int idx = idx0 + t;
    const bool valid = idx < fill;
    const int lane = t & 63;
    const int cidx = valid ? idx : fill - 1;       // clamp to a real edge
    const unsigned pk = sed[(size_t)b * SLOT + cidx];
    const int dla = (int)(pk >> 17);               // address-safe d_local
    const int s   = (int)(pk & 0x1FFFFu);
    const int dl  = valid ? dla : 128 + lane;      // sentinel: own segment

    // h1 = relu(base1[d] + base_s[s]); consecutive lanes share d -> L1 hits
    float a[9];
    {
        const float4* pb = reinterpret_cast<const float4*>(base1 + (size_t)(b * 128 + dla) * 12);
        float4 b0 = pb[0], b1 = pb[1];
        const float b8 = base1[(size_t)(b * 128 + dla) * 12 + 8];
        const float4* ps = reinterpret_cast<const float4*>(bases + (size_t)s * 16);
        float4 c0 = ps[0], c1 = ps[1];
        const float c8 = bases[(size_t)s * 16 + 8];
        a[0] = b0.x + c0.x; a[1] = b0.y + c0.y; a[2] = b0.z + c0.z; a[3] = b0.w + c0.w;
        a[4] = b1.x + c1.x; a[5] = b1.y + c1.y; a[6] = b1.z + c1.z; a[7] = b1.w + c1.w;
        a[8] = b8 + c8;
    }
    #pragma unroll
    for (int j = 0; j < 9; ++j) a[j] = fmaxf(a[j], 0.f);

    // h2 = relu(W2^T a + b2); weights via scalar loads (uniform addresses)
    float o[9];
    #pragma unroll
    for (int j = 0; j < 9; ++j) o[j] = feb2[j];
    #pragma unroll
    for (int i = 0; i < 9; ++i) {
        const float ai = a[i];
        #pragma unroll
        for (int j = 0; j < 9; ++j) o[j] = fmaf(ai, feW2[i * 9 + j], o[j]);
    }
    #pragma unroll
    for (int j = 0; j < 9; ++j) o[j] = fmaxf(o[j], 0.f);

    // segmented inclusive scan by dl over the 64-lane wave (dl sorted;
    // invalid lanes are isolated singleton segments -> garbage stays put)
    const int dprev = __shfl_up(dl, 1);
    const bool head = (lane == 0) || (dprev != dl);
    const unsigned long long hm = __ballot(head);
    const int dist = __clzll((long long)(hm << (63 - lane)));  // 0 if head
    #pragma unroll
    for (int off = 1; off < 64; off <<= 1) {
        const bool ok = (dist >= off);
        #pragma unroll
        for (int j = 0; j < 9; ++j) {
            const float ov = __shfl_up(o[j], off);
            o[j] += ok ? ov : 0.f;
        }
    }
    const bool tail = (lane == 63) || (((hm >> (lane + 1)) & 1ull) != 0ull);
    if (tail && valid) {                            // segment tail -> global m
        float* mp = m + (size_t)(b * 128 + dl) * 10;
        #pragma unroll
        for (int j = 0; j < 9; ++j) atomicAdd(mp + j, o[j]);
        atomicAdd(mp + 9, (float)(dist + 1));       // segment length = free count
    }
}

// ---------------- node round: W3/b3 + fx MLP + zero m + next bases ----------------
// No LDS: all weights wave-uniform -> scalar loads from constant cache.

__global__ __launch_bounds__(256) void node8_k(
    const float* __restrict__ Xin, float* __restrict__ m,
    const float* __restrict__ fxW1, const float* __restrict__ fxb1,
    const float* __restrict__ fxW2, const float* __restrict__ fxb2,
    const float* __restrict__ fxW3, const float* __restrict__ fxb3,
    const float* __restrict__ feW1, const float* __restrict__ feb1,
    const float* __restrict__ feW3, const float* __restrict__ feb3,
    float* __restrict__ Xout, float* __restrict__ base1out,
    float* __restrict__ basesout)
{
    const int n = blockIdx.x * 256 + threadIdx.x;
    if (n >= NN) return;

    float xr[16];
    {
        const float4* p = reinterpret_cast<const float4*>(Xin + (size_t)n * 16);
        #pragma unroll
        for (int q = 0; q < 4; ++q) {
            float4 v = p[q];
            xr[4*q] = v.x; xr[4*q+1] = v.y; xr[4*q+2] = v.z; xr[4*q+3] = v.w;
        }
    }
    float S[9], deg;
    float* mp = m + (size_t)n * 10;
    #pragma unroll
    for (int j = 0; j < 9; ++j) S[j] = mp[j];
    deg = mp[9];
    #pragma unroll
    for (int j = 0; j < 10; ++j) mp[j] = 0.f;    // ready for next round

    // m = W3^T S + deg * b3   (fe layer-3, hoisted from the edge loop)
    float mm[9];
    #pragma unroll
    for (int j = 0; j < 9; ++j) mm[j] = deg * feb3[j];
    #pragma unroll
    for (int i = 0; i < 9; ++i) {
        const float si = S[i];
        #pragma unroll
        for (int j = 0; j < 9; ++j) mm[j] = fmaf(si, feW3[i * 9 + j], mm[j]);
    }

    float h1[9];
    #pragma unroll
    for (int j = 0; j < 9; ++j) h1[j] = fxb1[j];
    #pragma unroll
    for (int i = 0; i < 16; ++i) {
        const float xi = xr[i];
        #pragma unroll
        for (int j = 0; j < 9; ++j) h1[j] = fmaf(xi, fxW1[i * 9 + j], h1[j]);
    }
    #pragma unroll
    for (int i = 0; i < 9; ++i) {
        const float xi = mm[i];
        #pragma unroll
        for (int j = 0; j < 9; ++j) h1[j] = fmaf(xi, fxW1[(16 + i) * 9 + j], h1[j]);
    }
    #pragma unroll
    for (int j = 0; j < 9; ++j) h1[j] = fmaxf(h1[j], 0.f);

    float h2[9];
    #pragma unroll
    for (int j = 0; j < 9; ++j) h2[j] = fxb2[j];
    #pragma unroll
    for (int i = 0; i < 9; ++i) {
        const float xi = h1[i];
        #pragma unroll
        for (int j = 0; j < 9; ++j) h2[j] = fmaf(xi, fxW2[i * 9 + j], h2[j]);
    }
    #pragma unroll
    for (int j = 0; j < 9; ++j) h2[j] = fmaxf(h2[j], 0.f);

    float o[16];
    #pragma unroll
    for (int k = 0; k < 16; ++k) o[k] = fxb3[k];
    #pragma unroll
    for (int j = 0; j < 9; ++j) {
        const float hj = h2[j];
        #pragma unroll
        for (int k = 0; k < 16; ++k) o[k] = fmaf(hj, fxW3[j * 16 + k], o[k]);
    }

    float4* po = reinterpret_cast<float4*>(Xout + (size_t)n * 16);
    #pragma unroll
    for (int q = 0; q < 4; ++q) {
        float4 v;
        v.x = o[4*q]; v.y = o[4*q+1]; v.z = o[4*q+2]; v.w = o[4*q+3];
        po[q] = v;
    }

    // base1 / base_s for NEXT round's edge kernel
    float bb[9];
    #pragma unroll
    for (int j = 0; j < 9; ++j) bb[j] = feb1[j];
    #pragma unroll
    for (int i = 0; i < 16; ++i) {
        const float xi = o[i];
        #pragma unroll
        for (int j = 0; j < 9; ++j) bb[j] = fmaf(xi, feW1[i * 9 + j], bb[j]);
    }
    float* bp = base1out + (size_t)n * 12;
    #pragma unroll
    for (int j = 0; j < 9; ++j) bp[j] = bb[j];

    float cc[9];
    #pragma unroll
    for (int j = 0; j < 9; ++j) cc[j] = 0.f;
    #pragma unroll
    for (int i = 0; i < 16; ++i) {
        const float xi = o[i];
        #pragma unroll
        for (int j = 0; j < 9; ++j) cc[j] = fmaf(xi, feW1[(16 + i) * 9 + j], cc[j]);
    }
    float* sp = basesout + (size_t)n * 16;
    #pragma unroll
    for (int j = 0; j < 9; ++j) sp[j] = cc[j];
}

extern "C" void kernel_launch(void* const* d_in, const int* in_sizes, int n_in,
                              void* d_out, int out_size, void* d_ws, size_t ws_size,
                              hipStream_t stream)
{
    (void)in_sizes; (void)n_in; (void)out_size; (void)ws_size;
    const float* X0   = (const float*)d_in[0];
    const int*   esrc = (const int*)d_in[1];
    const int*   edst = (const int*)d_in[2];
    const float* feW1 = (const float*)d_in[3];
    const float* feb1 = (const float*)d_in[4];
    const float* feW2 = (const float*)d_in[5];
    const float* feb2 = (const float*)d_in[6];
    const float* feW3 = (const float*)d_in[7];
    const float* feb3 = (const float*)d_in[8];
    const float* fxW1 = (const float*)d_in[9];
    const float* fxb1 = (const float*)d_in[10];
    const float* fxW2 = (const float*)d_in[11];
    const float* fxb2 = (const float*)d_in[12];
    const float* fxW3 = (const float*)d_in[13];
    const float* fxb3 = (const float*)d_in[14];
    float* out = (float*)d_out;

    // workspace layout (floats unless noted). total ~41 MB.
    float* base1  = (float*)d_ws;                         // NN*12
    float* bases  = base1 + (size_t)NN * 12;              // NN*16 (64B rows)
    float* mb     = bases + (size_t)NN * 16;              // NN*10 (9 sums + deg)
    int* gcursor  = (int*)(mb + (size_t)NN * 10);         // NBK (padded to 1024)
    unsigned* sed = (unsigned*)(gcursor + 1024);          // NBK*SLOT u32 = 25.6MB

    const dim3 thr(256);
    const dim3 gS(NBLK_SORT);          // 782
    const dim3 gL(NBK);                // 782
    const dim3 gE(NBK * (SLOT / 256)); // 25024
    const dim3 gN(NB_NODE);            // 391

    // ---- two-level sort (once per launch) ----
    hipMemsetAsync(gcursor, 0, NBK * sizeof(int), stream);
    bsort_k<<<gS, thr, 0, stream>>>(esrc, edst, gcursor, sed);
    lsort_k<<<gL, dim3(512), 0, stream>>>(sed, gcursor);

    // ---- round 0 ----
    base_k<<<gN, thr, 0, stream>>>(X0, feW1, feb1, base1, bases, mb);
    edge9_k<<<gE, thr, 0, stream>>>(base1, bases, sed, gcursor, feW2, feb2, mb);
    node8_k<<<gN, thr, 0, stream>>>(X0, mb, fxW1, fxb1, fxW2, fxb2, fxW3, fxb3,
                                    feW1, feb1, feW3, feb3, out, base1, bases);
    // ---- round 1 (node updates out in place; edge never reads X) ----
    edge9_k<<<gE, thr, 0, stream>>>(base1, bases, sed, gcursor, feW2, feb2, mb);
    node8_k<<<gN, thr, 0, stream>>>(out, mb, fxW1, fxb1, fxW2, fxb2, fxW3, fxb3,
                                    feW1, feb1, feW3, feb3, out, base1, bases);
    // ---- round 2 ----
    edge9_k<<<gE, thr, 0, stream>>>(base1, bases, sed, gcursor, feW2, feb2, mb);
    node8_k<<<gN, thr, 0, stream>>>(out, mb, fxW1, fxb1, fxW2, fxb2, fxW3, fxb3,
                                    feW1, feb1, feW3, feb3, out, base1, bases);
}